// Round 7
// baseline (565.922 us; speedup 1.0000x reference)
//
#include <hip/hip_runtime.h>
#include <hip/hip_fp16.h>
#include <stdint.h>

#define DIM 256
#define KE  768
#define NBLK 896   // = 2688/3: every block runs exactly 3 gemm tiles

typedef _Float16 half8 __attribute__((ext_vector_type(8)));
typedef float floatx4 __attribute__((ext_vector_type(4)));

// Workspace layout (bytes):
//   Xe    : 8192*768 ushort @ 0          (12,582,912)  [xh | xh | xl*2^11]
//   We    : 5376*768 ushort @ 12582912   ( 8,257,536)  [wh | wl*2^11 | wh]
//   wnorm : 5376 float      @ 20840448
//   xnorm : 8192 float      @ 20861952
//   best  : 24576 u64       @ 20894720   (level*8192+row) packed (d2<<32)|idx
//   ctrl  : 64 B            @ 21091328   [0] = grid-barrier counter
#define WS_WE_OFF    12582912
#define WS_WNORM_OFF 20840448
#define WS_XNORM_OFF 20861952
#define WS_BEST_OFF  20894720
#define WS_CTRL_OFF  21091328

// Software grid barrier: all NBLK blocks are guaranteed co-resident
// (LDS 32KB -> 5 blocks/CU, VGPR capped by launch_bounds -> capacity 1280
// blocks > 896). Bounded spin so a violated assumption degrades to a wrong
// answer instead of a hung container.
__device__ __forceinline__ void grid_barrier(unsigned* cnt, unsigned target) {
  __syncthreads();
  if (threadIdx.x == 0) {
    __threadfence();                       // release: flush L2-dirty stores
    atomicAdd(cnt, 1u);
    unsigned spins = 0;
    while (atomicAdd(cnt, 0u) < target && spins < 4000000u) {
      __builtin_amdgcn_s_sleep(2);
      ++spins;
    }
    __threadfence();                       // acquire: invalidate stale lines
  }
  __syncthreads();
}

// Single persistent kernel: conv -> barrier -> gemm (3 tiles/block) ->
// barrier -> finalize. Eliminates 2 dispatch boundaries (~13 us each
// measured across rounds 0/4/5). Phase bodies identical to round-5 kernels
// (162.8 us, absmax 0.0).
__global__ __launch_bounds__(256, 5) void fused_kernel(
    const float* __restrict__ x, const float* __restrict__ w1,
    const float* __restrict__ w2, const float* __restrict__ w3,
    ushort* __restrict__ Xe, ushort* __restrict__ We,
    float* __restrict__ wnorm, float* __restrict__ xnorm,
    unsigned long long* __restrict__ best, unsigned* __restrict__ ctrl,
    float* __restrict__ out) {
  __shared__ __align__(16) ushort As[128 * 64];  // 16KB, XOR-swizzled chunks
  __shared__ __align__(16) ushort Bs[128 * 64];
  // red[2][128] u64 (2 KB) aliases As: only used after the K-loop's final
  // __syncthreads(); tile-loop top barrier protects across tiles.
  unsigned long long (*red)[128] = (unsigned long long (*)[128])As;

  const int t = threadIdx.x;
  const int wv = t >> 6;
  const int lane = t & 63;

  // ===== Phase 1: conv (fp32 norm + fp16 hi/lo expanded layouts) + best init
  if (blockIdx.x < 96) best[blockIdx.x * 256 + t] = ~0ull;
  for (int task = blockIdx.x * 4 + wv; task < 13568; task += NBLK * 4) {
    const float* src; ushort* dst; float* ndst; int isx;
    if (task < 8192) {
      src = x + (size_t)task * DIM; dst = Xe + (size_t)task * KE;
      ndst = xnorm + task; isx = 1;
    } else {
      int wi = task - 8192;
      if (wi < 256)       src = w1 + (size_t)wi * DIM;
      else if (wi < 1280) src = w2 + (size_t)(wi - 256) * DIM;
      else                src = w3 + (size_t)(wi - 1280) * DIM;
      dst = We + (size_t)wi * KE; ndst = wnorm + wi; isx = 0;
    }
    float4 v = *(const float4*)(src + lane * 4);
    float fv[4] = {v.x, v.y, v.z, v.w};
    float s = fv[0]*fv[0] + fv[1]*fv[1] + fv[2]*fv[2] + fv[3]*fv[3];
    #pragma unroll
    for (int o = 32; o > 0; o >>= 1) s += __shfl_xor(s, o);
    if (lane == 0) *ndst = s;

    ushort h[4], l[4];
    #pragma unroll
    for (int e = 0; e < 4; ++e) {
      __half hh = __float2half(fv[e]);
      float hf = __half2float(hh);
      __half ll = __float2half((fv[e] - hf) * 2048.0f);  // scaled lo
      h[e] = __half_as_ushort(hh);
      l[e] = __half_as_ushort(ll);
    }
    ushort4 h4 = make_ushort4(h[0], h[1], h[2], h[3]);
    ushort4 l4 = make_ushort4(l[0], l[1], l[2], l[3]);
    if (isx) {  // [xh | xh | xl2]
      *(ushort4*)(dst + lane * 4)        = h4;
      *(ushort4*)(dst + 256 + lane * 4)  = h4;
      *(ushort4*)(dst + 512 + lane * 4)  = l4;
    } else {    // [wh | wl2 | wh]
      *(ushort4*)(dst + lane * 4)        = h4;
      *(ushort4*)(dst + 256 + lane * 4)  = l4;
      *(ushort4*)(dst + 512 + lane * 4)  = h4;
    }
  }
  grid_barrier(ctrl, NBLK);

  // ===== Phase 2: gemm — 128x128 tile over K=768, fused per-row argmin.
  const int ln = lane & 15, q = lane >> 4;
  const int wm = (wv >> 1) * 64, wn = (wv & 1) * 64;

  for (int tb = blockIdx.x; tb < 2688; tb += NBLK) {
    const int cb = tb % 42;
    const int r0 = (tb / 42) * 128;
    const int n0 = cb * 128;
    int level, lbase;
    if (cb < 2)       { level = 0; lbase = 0; }
    else if (cb < 10) { level = 1; lbase = 256; }
    else              { level = 2; lbase = 1280; }

    __syncthreads();  // protect red/As alias + LDS reuse across tiles

    floatx4 acc[4][4];
    #pragma unroll
    for (int i = 0; i < 4; ++i)
      #pragma unroll
      for (int j = 0; j < 4; ++j) acc[i][j] = (floatx4)0.0f;

    for (int k0 = 0; k0 < KE; k0 += 64) {
      if (k0 == 256) {  // hh phase done: scale so cross terms (2^11) match
        #pragma unroll
        for (int i = 0; i < 4; ++i)
          #pragma unroll
          for (int j = 0; j < 4; ++j) acc[i][j] *= 2048.0f;
      }
      // Stage A/B tiles: chunk p -> (row m = p>>3, colchunk c = (p&7)^(m&7))
      #pragma unroll
      for (int it = 0; it < 4; ++it) {
        int p = it * 256 + t;
        int m = p >> 3;
        int c = (p & 7) ^ (m & 7);
        const ushort* ga = Xe + (size_t)(r0 + m) * KE + k0 + c * 8;
        const ushort* gb = We + (size_t)(n0 + m) * KE + k0 + c * 8;
        int lbc = it * 256 + (t & 192);  // wave-uniform
        __builtin_amdgcn_global_load_lds(
            (const __attribute__((address_space(1))) void*)ga,
            (__attribute__((address_space(3))) void*)(As + lbc * 8), 16, 0, 0);
        __builtin_amdgcn_global_load_lds(
            (const __attribute__((address_space(1))) void*)gb,
            (__attribute__((address_space(3))) void*)(Bs + lbc * 8), 16, 0, 0);
      }
      __syncthreads();
      #pragma unroll
      for (int s = 0; s < 2; ++s) {
        half8 a[4], b[4];
        #pragma unroll
        for (int mt = 0; mt < 4; ++mt) {
          int m = wm + mt * 16 + ln;
          int pos = m * 8 + ((s * 4 + q) ^ (m & 7));
          a[mt] = *(const half8*)&As[pos * 8];
        }
        #pragma unroll
        for (int nt = 0; nt < 4; ++nt) {
          int n = wn + nt * 16 + ln;
          int pos = n * 8 + ((s * 4 + q) ^ (n & 7));
          b[nt] = *(const half8*)&Bs[pos * 8];
        }
        #pragma unroll
        for (int mt = 0; mt < 4; ++mt)
          #pragma unroll
          for (int nt = 0; nt < 4; ++nt)
            acc[mt][nt] = __builtin_amdgcn_mfma_f32_16x16x32_f16(
                a[mt], b[nt], acc[mt][nt], 0, 0, 0);
      }
      __syncthreads();
    }

    // acc = 2^11 * dot. d2 = xn + wn - acc * 2^-10.
    float wnv[4];
    #pragma unroll
    for (int nt = 0; nt < 4; ++nt) wnv[nt] = wnorm[n0 + wn + nt * 16 + ln];

    #pragma unroll
    for (int mt = 0; mt < 4; ++mt) {
      #pragma unroll
      for (int r = 0; r < 4; ++r) {
        int rowl = wm + mt * 16 + q * 4 + r;
        float xnv = xnorm[r0 + rowl];
        unsigned long long bp = ~0ull;
        #pragma unroll
        for (int nt = 0; nt < 4; ++nt) {
          float d2 = fmaxf(xnv + wnv[nt] - acc[mt][nt][r] * 0.0009765625f,
                           0.0f);
          unsigned col = (unsigned)(n0 + wn + nt * 16 + ln - lbase);
          unsigned long long p =
              ((unsigned long long)__float_as_uint(d2) << 32) | col;
          bp = (p < bp) ? p : bp;
        }
        #pragma unroll
        for (int off = 1; off < 16; off <<= 1) {
          unsigned long long o = __shfl_xor(bp, off);
          bp = (o < bp) ? o : bp;
        }
        if (ln == 0) red[wv & 1][rowl] = bp;
      }
    }
    __syncthreads();
    if (t < 128) {
      unsigned long long a = red[0][t], b = red[1][t];
      unsigned long long m = (a < b) ? a : b;
      atomicMin(&best[level * 8192 + r0 + t], m);
    }
  }
  grid_barrier(ctrl, 2 * NBLK);

  // ===== Phase 3: finalize — coords + exact fp32 quantization error.
  for (int task = blockIdx.x * 4 + wv; task < 24576; task += NBLK * 4) {
    int level = task >> 13;
    int row = task & 8191;
    const float* w; unsigned side;
    if (level == 0)      { w = w1; side = 16; }
    else if (level == 1) { w = w2; side = 32; }
    else                 { w = w3; side = 64; }
    unsigned idx = (unsigned)(best[task] & 0xFFFFFFFFull);
    if (idx >= side * side) idx = 0;   // defensive: never fault
    float4 xv = *(const float4*)(x + (size_t)row * DIM + lane * 4);
    float4 wvv = *(const float4*)(w + (size_t)idx * DIM + lane * 4);
    float dx = xv.x - wvv.x, dy = xv.y - wvv.y;
    float dz = xv.z - wvv.z, dw = xv.w - wvv.w;
    float s = dx * dx + dy * dy + dz * dz + dw * dw;
    #pragma unroll
    for (int o = 32; o > 0; o >>= 1) s += __shfl_xor(s, o);
    if (lane == 0) {
      out[level * 16384 + row * 2 + 0] = (float)(idx / side);
      out[level * 16384 + row * 2 + 1] = (float)(idx % side);
      out[49152 + level * 8192 + row] = sqrtf(s);
    }
  }
}

extern "C" void kernel_launch(void* const* d_in, const int* in_sizes, int n_in,
                              void* d_out, int out_size, void* d_ws, size_t ws_size,
                              hipStream_t stream) {
  const float* x  = (const float*)d_in[0];
  const float* w1 = (const float*)d_in[1];
  const float* w2 = (const float*)d_in[2];
  const float* w3 = (const float*)d_in[3];
  ushort* Xe = (ushort*)d_ws;
  ushort* We = (ushort*)((char*)d_ws + WS_WE_OFF);
  float* wnorm = (float*)((char*)d_ws + WS_WNORM_OFF);
  float* xnorm = (float*)((char*)d_ws + WS_XNORM_OFF);
  unsigned long long* best = (unsigned long long*)((char*)d_ws + WS_BEST_OFF);
  unsigned* ctrl = (unsigned*)((char*)d_ws + WS_CTRL_OFF);

  hipMemsetAsync(ctrl, 0, 64, stream);
  fused_kernel<<<NBLK, 256, 0, stream>>>(x, w1, w2, w3, Xe, We, wnorm, xnorm,
                                         best, ctrl, (float*)d_out);
}

// Round 8
// 434.474 us; speedup vs baseline: 1.3025x; 1.3025x over previous
//
#include <hip/hip_runtime.h>
#include <hip/hip_fp16.h>
#include <stdint.h>

#define DIM 256
#define KE  768
#define NBLK 896   // = 2688/3: every block runs exactly 3 gemm tiles

typedef _Float16 half8 __attribute__((ext_vector_type(8)));
typedef float floatx4 __attribute__((ext_vector_type(4)));

// Workspace layout (bytes):
//   Xe    : 8192*768 ushort @ 0          (12,582,912)  [xh | xh | xl*2^11]
//   We    : 5376*768 ushort @ 12582912   ( 8,257,536)  [wh | wl*2^11 | wh]
//   wnorm : 5376 float      @ 20840448
//   xnorm : 8192 float      @ 20861952
//   best  : 24576 u64       @ 20894720   (level*8192+row) packed (d2<<32)|idx
//   ctrl  : 64 B            @ 21091328   [0] = grid-barrier counter
#define WS_WE_OFF    12582912
#define WS_WNORM_OFF 20840448
#define WS_XNORM_OFF 20861952
#define WS_BEST_OFF  20894720
#define WS_CTRL_OFF  21091328

// Software grid barrier. Residency: LDS 32KB -> 5 blocks/CU; VGPR <=128
// (launch_bounds 256,4) -> >=4 blocks/CU -> capacity >=1024 > NBLK=896.
// Poll uses a device-scope atomic LOAD (agent scope): required for
// cross-XCD visibility (plain volatile load can spin on stale local L2).
// Bounded spin: a violated assumption degrades to a wrong answer, not hang.
__device__ __forceinline__ void grid_barrier(unsigned* cnt, unsigned target) {
  __syncthreads();
  if (threadIdx.x == 0) {
    __threadfence();                       // release
    __hip_atomic_fetch_add(cnt, 1u, __ATOMIC_RELAXED,
                           __HIP_MEMORY_SCOPE_AGENT);
    unsigned spins = 0;
    while (__hip_atomic_load(cnt, __ATOMIC_RELAXED,
                             __HIP_MEMORY_SCOPE_AGENT) < target &&
           spins < 4000000u) {
      __builtin_amdgcn_s_sleep(2);
      ++spins;
    }
    __threadfence();                       // acquire
  }
  __syncthreads();
}

// Single persistent kernel: conv -> barrier -> gemm (3 tiles/block) ->
// barrier -> finalize. Eliminates 2 dispatch boundaries (~13 us each).
// launch_bounds (256,4): VGPR cap 128 — round 7's (256,5) capped at ~96
// and spilled acc[][] to scratch (VGPR=48, WRITE_SIZE=376MB, 537us).
__global__ __launch_bounds__(256, 4) void fused_kernel(
    const float* __restrict__ x, const float* __restrict__ w1,
    const float* __restrict__ w2, const float* __restrict__ w3,
    ushort* __restrict__ Xe, ushort* __restrict__ We,
    float* __restrict__ wnorm, float* __restrict__ xnorm,
    unsigned long long* __restrict__ best, unsigned* __restrict__ ctrl,
    float* __restrict__ out) {
  __shared__ __align__(16) ushort As[128 * 64];  // 16KB, XOR-swizzled chunks
  __shared__ __align__(16) ushort Bs[128 * 64];
  // red[2][128] u64 (2 KB) aliases As: only used after the K-loop's final
  // __syncthreads(); tile-loop top barrier protects across tiles.
  unsigned long long (*red)[128] = (unsigned long long (*)[128])As;

  const int t = threadIdx.x;
  const int wv = t >> 6;
  const int lane = t & 63;

  // ===== Phase 1: conv (fp32 norm + fp16 hi/lo expanded layouts) + best init
  if (blockIdx.x < 96) best[blockIdx.x * 256 + t] = ~0ull;
  for (int task = blockIdx.x * 4 + wv; task < 13568; task += NBLK * 4) {
    const float* src; ushort* dst; float* ndst; int isx;
    if (task < 8192) {
      src = x + (size_t)task * DIM; dst = Xe + (size_t)task * KE;
      ndst = xnorm + task; isx = 1;
    } else {
      int wi = task - 8192;
      if (wi < 256)       src = w1 + (size_t)wi * DIM;
      else if (wi < 1280) src = w2 + (size_t)(wi - 256) * DIM;
      else                src = w3 + (size_t)(wi - 1280) * DIM;
      dst = We + (size_t)wi * KE; ndst = wnorm + wi; isx = 0;
    }
    float4 v = *(const float4*)(src + lane * 4);
    float fv[4] = {v.x, v.y, v.z, v.w};
    float s = fv[0]*fv[0] + fv[1]*fv[1] + fv[2]*fv[2] + fv[3]*fv[3];
    #pragma unroll
    for (int o = 32; o > 0; o >>= 1) s += __shfl_xor(s, o);
    if (lane == 0) *ndst = s;

    ushort h[4], l[4];
    #pragma unroll
    for (int e = 0; e < 4; ++e) {
      __half hh = __float2half(fv[e]);
      float hf = __half2float(hh);
      __half ll = __float2half((fv[e] - hf) * 2048.0f);  // scaled lo
      h[e] = __half_as_ushort(hh);
      l[e] = __half_as_ushort(ll);
    }
    ushort4 h4 = make_ushort4(h[0], h[1], h[2], h[3]);
    ushort4 l4 = make_ushort4(l[0], l[1], l[2], l[3]);
    if (isx) {  // [xh | xh | xl2]
      *(ushort4*)(dst + lane * 4)        = h4;
      *(ushort4*)(dst + 256 + lane * 4)  = h4;
      *(ushort4*)(dst + 512 + lane * 4)  = l4;
    } else {    // [wh | wl2 | wh]
      *(ushort4*)(dst + lane * 4)        = h4;
      *(ushort4*)(dst + 256 + lane * 4)  = l4;
      *(ushort4*)(dst + 512 + lane * 4)  = h4;
    }
  }
  grid_barrier(ctrl, NBLK);

  // ===== Phase 2: gemm — 128x128 tile over K=768, fused per-row argmin.
  const int ln = lane & 15, q = lane >> 4;
  const int wm = (wv >> 1) * 64, wn = (wv & 1) * 64;

  for (int tb = blockIdx.x; tb < 2688; tb += NBLK) {
    const int cb = tb % 42;
    const int r0 = (tb / 42) * 128;
    const int n0 = cb * 128;
    int level, lbase;
    if (cb < 2)       { level = 0; lbase = 0; }
    else if (cb < 10) { level = 1; lbase = 256; }
    else              { level = 2; lbase = 1280; }

    __syncthreads();  // protect red/As alias + LDS reuse across tiles

    floatx4 acc[4][4];
    #pragma unroll
    for (int i = 0; i < 4; ++i)
      #pragma unroll
      for (int j = 0; j < 4; ++j) acc[i][j] = (floatx4)0.0f;

    for (int k0 = 0; k0 < KE; k0 += 64) {
      if (k0 == 256) {  // hh phase done: scale so cross terms (2^11) match
        #pragma unroll
        for (int i = 0; i < 4; ++i)
          #pragma unroll
          for (int j = 0; j < 4; ++j) acc[i][j] *= 2048.0f;
      }
      // Stage A/B tiles: chunk p -> (row m = p>>3, colchunk c = (p&7)^(m&7))
      #pragma unroll
      for (int it = 0; it < 4; ++it) {
        int p = it * 256 + t;
        int m = p >> 3;
        int c = (p & 7) ^ (m & 7);
        const ushort* ga = Xe + (size_t)(r0 + m) * KE + k0 + c * 8;
        const ushort* gb = We + (size_t)(n0 + m) * KE + k0 + c * 8;
        int lbc = it * 256 + (t & 192);  // wave-uniform
        __builtin_amdgcn_global_load_lds(
            (const __attribute__((address_space(1))) void*)ga,
            (__attribute__((address_space(3))) void*)(As + lbc * 8), 16, 0, 0);
        __builtin_amdgcn_global_load_lds(
            (const __attribute__((address_space(1))) void*)gb,
            (__attribute__((address_space(3))) void*)(Bs + lbc * 8), 16, 0, 0);
      }
      __syncthreads();
      #pragma unroll
      for (int s = 0; s < 2; ++s) {
        half8 a[4], b[4];
        #pragma unroll
        for (int mt = 0; mt < 4; ++mt) {
          int m = wm + mt * 16 + ln;
          int pos = m * 8 + ((s * 4 + q) ^ (m & 7));
          a[mt] = *(const half8*)&As[pos * 8];
        }
        #pragma unroll
        for (int nt = 0; nt < 4; ++nt) {
          int n = wn + nt * 16 + ln;
          int pos = n * 8 + ((s * 4 + q) ^ (n & 7));
          b[nt] = *(const half8*)&Bs[pos * 8];
        }
        #pragma unroll
        for (int mt = 0; mt < 4; ++mt)
          #pragma unroll
          for (int nt = 0; nt < 4; ++nt)
            acc[mt][nt] = __builtin_amdgcn_mfma_f32_16x16x32_f16(
                a[mt], b[nt], acc[mt][nt], 0, 0, 0);
      }
      __syncthreads();
    }

    // acc = 2^11 * dot. d2 = xn + wn - acc * 2^-10.
    float wnv[4];
    #pragma unroll
    for (int nt = 0; nt < 4; ++nt) wnv[nt] = wnorm[n0 + wn + nt * 16 + ln];

    #pragma unroll
    for (int mt = 0; mt < 4; ++mt) {
      #pragma unroll
      for (int r = 0; r < 4; ++r) {
        int rowl = wm + mt * 16 + q * 4 + r;
        float xnv = xnorm[r0 + rowl];
        unsigned long long bp = ~0ull;
        #pragma unroll
        for (int nt = 0; nt < 4; ++nt) {
          float d2 = fmaxf(xnv + wnv[nt] - acc[mt][nt][r] * 0.0009765625f,
                           0.0f);
          unsigned col = (unsigned)(n0 + wn + nt * 16 + ln - lbase);
          unsigned long long p =
              ((unsigned long long)__float_as_uint(d2) << 32) | col;
          bp = (p < bp) ? p : bp;
        }
        #pragma unroll
        for (int off = 1; off < 16; off <<= 1) {
          unsigned long long o = __shfl_xor(bp, off);
          bp = (o < bp) ? o : bp;
        }
        if (ln == 0) red[wv & 1][rowl] = bp;
      }
    }
    __syncthreads();
    if (t < 128) {
      unsigned long long a = red[0][t], b = red[1][t];
      unsigned long long m = (a < b) ? a : b;
      atomicMin(&best[level * 8192 + r0 + t], m);
    }
  }
  grid_barrier(ctrl, 2 * NBLK);

  // ===== Phase 3: finalize — coords + exact fp32 quantization error.
  for (int task = blockIdx.x * 4 + wv; task < 24576; task += NBLK * 4) {
    int level = task >> 13;
    int row = task & 8191;
    const float* w; unsigned side;
    if (level == 0)      { w = w1; side = 16; }
    else if (level == 1) { w = w2; side = 32; }
    else                 { w = w3; side = 64; }
    unsigned idx = (unsigned)(best[task] & 0xFFFFFFFFull);
    if (idx >= side * side) idx = 0;   // defensive: never fault
    float4 xv = *(const float4*)(x + (size_t)row * DIM + lane * 4);
    float4 wvv = *(const float4*)(w + (size_t)idx * DIM + lane * 4);
    float dx = xv.x - wvv.x, dy = xv.y - wvv.y;
    float dz = xv.z - wvv.z, dw = xv.w - wvv.w;
    float s = dx * dx + dy * dy + dz * dz + dw * dw;
    #pragma unroll
    for (int o = 32; o > 0; o >>= 1) s += __shfl_xor(s, o);
    if (lane == 0) {
      out[level * 16384 + row * 2 + 0] = (float)(idx / side);
      out[level * 16384 + row * 2 + 1] = (float)(idx % side);
      out[49152 + level * 8192 + row] = sqrtf(s);
    }
  }
}

extern "C" void kernel_launch(void* const* d_in, const int* in_sizes, int n_in,
                              void* d_out, int out_size, void* d_ws, size_t ws_size,
                              hipStream_t stream) {
  const float* x  = (const float*)d_in[0];
  const float* w1 = (const float*)d_in[1];
  const float* w2 = (const float*)d_in[2];
  const float* w3 = (const float*)d_in[3];
  ushort* Xe = (ushort*)d_ws;
  ushort* We = (ushort*)((char*)d_ws + WS_WE_OFF);
  float* wnorm = (float*)((char*)d_ws + WS_WNORM_OFF);
  float* xnorm = (float*)((char*)d_ws + WS_XNORM_OFF);
  unsigned long long* best = (unsigned long long*)((char*)d_ws + WS_BEST_OFF);
  unsigned* ctrl = (unsigned*)((char*)d_ws + WS_CTRL_OFF);

  hipMemsetAsync(ctrl, 0, 64, stream);
  fused_kernel<<<NBLK, 256, 0, stream>>>(x, w1, w2, w3, Xe, We, wnorm, xnorm,
                                         best, ctrl, (float*)d_out);
}

// Round 9
// 355.630 us; speedup vs baseline: 1.5913x; 1.2217x over previous
//
#include <hip/hip_runtime.h>
#include <hip/hip_fp16.h>
#include <stdint.h>

#define DIM 256
#define KE  768
#define NBLK 672   // needs ceil(672/256)=3 blocks/CU resident; (256,3) guarantees it

typedef _Float16 half8 __attribute__((ext_vector_type(8)));
typedef float floatx4 __attribute__((ext_vector_type(4)));

// Workspace layout (bytes):
//   Xe    : 8192*768 ushort @ 0          (12,582,912)  [xh | xh | xl*2^11]
//   We    : 5376*768 ushort @ 12582912   ( 8,257,536)  [wh | wl*2^11 | wh]
//   wnorm : 5376 float      @ 20840448
//   xnorm : 8192 float      @ 20861952
//   best  : 24576 u64       @ 20894720   (level*8192+row) packed (d2<<32)|idx
//   ctrl  : 256 B           @ 21091328   [0]=grid-barrier counter, [32]=tile counter
#define WS_WE_OFF    12582912
#define WS_WNORM_OFF 20840448
#define WS_XNORM_OFF 20861952
#define WS_BEST_OFF  20894720
#define WS_CTRL_OFF  21091328

// Software grid barrier. Residency proof: LDS 32KB -> 5 blocks/CU;
// __launch_bounds__(256,3) -> 3 waves/EU -> 12 waves/CU -> 3 blocks/CU;
// capacity 256*3 = 768 >= NBLK=672. VGPR cap 512/3~168 >= ~148 used by the
// gemm body (84 arch + 64 acc) -> NO spill (rounds 7/8 spilled because
// (256,5)/(256,4) capped at 102/128, squeezing arch VGPR to 48/64).
// Bounded spin: violated assumption -> wrong answer, not a hung container.
__device__ __forceinline__ void grid_barrier(unsigned* cnt, unsigned target) {
  __syncthreads();
  if (threadIdx.x == 0) {
    __threadfence();                       // release
    __hip_atomic_fetch_add(cnt, 1u, __ATOMIC_RELAXED,
                           __HIP_MEMORY_SCOPE_AGENT);
    unsigned spins = 0;
    while (__hip_atomic_load(cnt, __ATOMIC_RELAXED,
                             __HIP_MEMORY_SCOPE_AGENT) < target &&
           spins < 4000000u) {
      __builtin_amdgcn_s_sleep(2);
      ++spins;
    }
    __threadfence();                       // acquire
  }
  __syncthreads();
}

// Single persistent kernel: conv -> barrier -> gemm (work-stolen tiles) ->
// barrier -> finalize. Eliminates 2 dispatch boundaries (~13-20 us each).
__global__ __launch_bounds__(256, 3) void fused_kernel(
    const float* __restrict__ x, const float* __restrict__ w1,
    const float* __restrict__ w2, const float* __restrict__ w3,
    ushort* __restrict__ Xe, ushort* __restrict__ We,
    float* __restrict__ wnorm, float* __restrict__ xnorm,
    unsigned long long* __restrict__ best, unsigned* __restrict__ ctrl,
    float* __restrict__ out) {
  __shared__ __align__(16) ushort As[128 * 64];  // 16KB, XOR-swizzled chunks
  __shared__ __align__(16) ushort Bs[128 * 64];
  __shared__ int stb;
  // red[2][128] u64 (2 KB) aliases As: only used after the K-loop's final
  // __syncthreads(); tile-loop top barrier protects across tiles.
  unsigned long long (*red)[128] = (unsigned long long (*)[128])As;

  const int t = threadIdx.x;
  const int wv = t >> 6;
  const int lane = t & 63;

  // ===== Phase 1: conv (fp32 norm + fp16 hi/lo expanded layouts) + best init
  if (blockIdx.x < 96) best[blockIdx.x * 256 + t] = ~0ull;
  for (int task = blockIdx.x * 4 + wv; task < 13568; task += NBLK * 4) {
    const float* src; ushort* dst; float* ndst; int isx;
    if (task < 8192) {
      src = x + (size_t)task * DIM; dst = Xe + (size_t)task * KE;
      ndst = xnorm + task; isx = 1;
    } else {
      int wi = task - 8192;
      if (wi < 256)       src = w1 + (size_t)wi * DIM;
      else if (wi < 1280) src = w2 + (size_t)(wi - 256) * DIM;
      else                src = w3 + (size_t)(wi - 1280) * DIM;
      dst = We + (size_t)wi * KE; ndst = wnorm + wi; isx = 0;
    }
    float4 v = *(const float4*)(src + lane * 4);
    float fv[4] = {v.x, v.y, v.z, v.w};
    float s = fv[0]*fv[0] + fv[1]*fv[1] + fv[2]*fv[2] + fv[3]*fv[3];
    #pragma unroll
    for (int o = 32; o > 0; o >>= 1) s += __shfl_xor(s, o);
    if (lane == 0) *ndst = s;

    ushort h[4], l[4];
    #pragma unroll
    for (int e = 0; e < 4; ++e) {
      __half hh = __float2half(fv[e]);
      float hf = __half2float(hh);
      __half ll = __float2half((fv[e] - hf) * 2048.0f);  // scaled lo
      h[e] = __half_as_ushort(hh);
      l[e] = __half_as_ushort(ll);
    }
    ushort4 h4 = make_ushort4(h[0], h[1], h[2], h[3]);
    ushort4 l4 = make_ushort4(l[0], l[1], l[2], l[3]);
    if (isx) {  // [xh | xh | xl2]
      *(ushort4*)(dst + lane * 4)        = h4;
      *(ushort4*)(dst + 256 + lane * 4)  = h4;
      *(ushort4*)(dst + 512 + lane * 4)  = l4;
    } else {    // [wh | wl2 | wh]
      *(ushort4*)(dst + lane * 4)        = h4;
      *(ushort4*)(dst + 256 + lane * 4)  = l4;
      *(ushort4*)(dst + 512 + lane * 4)  = h4;
    }
  }
  grid_barrier(ctrl, NBLK);

  // ===== Phase 2: gemm — 128x128 tile over K=768, fused per-row argmin.
  // Tiles are work-stolen via a global counter: balanced ~10.5 tiles/CU
  // makespan regardless of block->CU placement.
  const int ln = lane & 15, q = lane >> 4;
  const int wm = (wv >> 1) * 64, wn = (wv & 1) * 64;
  unsigned* work = ctrl + 32;   // 128 B from the barrier counter

  while (true) {
    if (t == 0) stb = (int)atomicAdd(work, 1u);
    __syncthreads();  // broadcast stb; also protects red/As alias across tiles
    const int tb = stb;
    if (tb >= 2688) break;
    const int cb = tb % 42;
    const int r0 = (tb / 42) * 128;
    const int n0 = cb * 128;
    int level, lbase;
    if (cb < 2)       { level = 0; lbase = 0; }
    else if (cb < 10) { level = 1; lbase = 256; }
    else              { level = 2; lbase = 1280; }

    floatx4 acc[4][4];
    #pragma unroll
    for (int i = 0; i < 4; ++i)
      #pragma unroll
      for (int j = 0; j < 4; ++j) acc[i][j] = (floatx4)0.0f;

    for (int k0 = 0; k0 < KE; k0 += 64) {
      if (k0 == 256) {  // hh phase done: scale so cross terms (2^11) match
        #pragma unroll
        for (int i = 0; i < 4; ++i)
          #pragma unroll
          for (int j = 0; j < 4; ++j) acc[i][j] *= 2048.0f;
      }
      // Stage A/B tiles: chunk p -> (row m = p>>3, colchunk c = (p&7)^(m&7))
      #pragma unroll
      for (int it = 0; it < 4; ++it) {
        int p = it * 256 + t;
        int m = p >> 3;
        int c = (p & 7) ^ (m & 7);
        const ushort* ga = Xe + (size_t)(r0 + m) * KE + k0 + c * 8;
        const ushort* gb = We + (size_t)(n0 + m) * KE + k0 + c * 8;
        int lbc = it * 256 + (t & 192);  // wave-uniform
        __builtin_amdgcn_global_load_lds(
            (const __attribute__((address_space(1))) void*)ga,
            (__attribute__((address_space(3))) void*)(As + lbc * 8), 16, 0, 0);
        __builtin_amdgcn_global_load_lds(
            (const __attribute__((address_space(1))) void*)gb,
            (__attribute__((address_space(3))) void*)(Bs + lbc * 8), 16, 0, 0);
      }
      __syncthreads();
      #pragma unroll
      for (int s = 0; s < 2; ++s) {
        half8 a[4], b[4];
        #pragma unroll
        for (int mt = 0; mt < 4; ++mt) {
          int m = wm + mt * 16 + ln;
          int pos = m * 8 + ((s * 4 + q) ^ (m & 7));
          a[mt] = *(const half8*)&As[pos * 8];
        }
        #pragma unroll
        for (int nt = 0; nt < 4; ++nt) {
          int n = wn + nt * 16 + ln;
          int pos = n * 8 + ((s * 4 + q) ^ (n & 7));
          b[nt] = *(const half8*)&Bs[pos * 8];
        }
        #pragma unroll
        for (int mt = 0; mt < 4; ++mt)
          #pragma unroll
          for (int nt = 0; nt < 4; ++nt)
            acc[mt][nt] = __builtin_amdgcn_mfma_f32_16x16x32_f16(
                a[mt], b[nt], acc[mt][nt], 0, 0, 0);
      }
      __syncthreads();
    }

    // acc = 2^11 * dot. d2 = xn + wn - acc * 2^-10.
    float wnv[4];
    #pragma unroll
    for (int nt = 0; nt < 4; ++nt) wnv[nt] = wnorm[n0 + wn + nt * 16 + ln];

    #pragma unroll
    for (int mt = 0; mt < 4; ++mt) {
      #pragma unroll
      for (int r = 0; r < 4; ++r) {
        int rowl = wm + mt * 16 + q * 4 + r;
        float xnv = xnorm[r0 + rowl];
        unsigned long long bp = ~0ull;
        #pragma unroll
        for (int nt = 0; nt < 4; ++nt) {
          float d2 = fmaxf(xnv + wnv[nt] - acc[mt][nt][r] * 0.0009765625f,
                           0.0f);
          unsigned col = (unsigned)(n0 + wn + nt * 16 + ln - lbase);
          unsigned long long p =
              ((unsigned long long)__float_as_uint(d2) << 32) | col;
          bp = (p < bp) ? p : bp;
        }
        #pragma unroll
        for (int off = 1; off < 16; off <<= 1) {
          unsigned long long o = __shfl_xor(bp, off);
          bp = (o < bp) ? o : bp;
        }
        if (ln == 0) red[wv & 1][rowl] = bp;
      }
    }
    __syncthreads();
    if (t < 128) {
      unsigned long long a = red[0][t], b = red[1][t];
      unsigned long long m = (a < b) ? a : b;
      atomicMin(&best[level * 8192 + r0 + t], m);
    }
  }
  grid_barrier(ctrl, 2 * NBLK);

  // ===== Phase 3: finalize — coords + exact fp32 quantization error.
  for (int task = blockIdx.x * 4 + wv; task < 24576; task += NBLK * 4) {
    int level = task >> 13;
    int row = task & 8191;
    const float* w; unsigned side;
    if (level == 0)      { w = w1; side = 16; }
    else if (level == 1) { w = w2; side = 32; }
    else                 { w = w3; side = 64; }
    unsigned idx = (unsigned)(best[task] & 0xFFFFFFFFull);
    if (idx >= side * side) idx = 0;   // defensive: never fault
    float4 xv = *(const float4*)(x + (size_t)row * DIM + lane * 4);
    float4 wvv = *(const float4*)(w + (size_t)idx * DIM + lane * 4);
    float dx = xv.x - wvv.x, dy = xv.y - wvv.y;
    float dz = xv.z - wvv.z, dw = xv.w - wvv.w;
    float s = dx * dx + dy * dy + dz * dz + dw * dw;
    #pragma unroll
    for (int o = 32; o > 0; o >>= 1) s += __shfl_xor(s, o);
    if (lane == 0) {
      out[level * 16384 + row * 2 + 0] = (float)(idx / side);
      out[level * 16384 + row * 2 + 1] = (float)(idx % side);
      out[49152 + level * 8192 + row] = sqrtf(s);
    }
  }
}

extern "C" void kernel_launch(void* const* d_in, const int* in_sizes, int n_in,
                              void* d_out, int out_size, void* d_ws, size_t ws_size,
                              hipStream_t stream) {
  const float* x  = (const float*)d_in[0];
  const float* w1 = (const float*)d_in[1];
  const float* w2 = (const float*)d_in[2];
  const float* w3 = (const float*)d_in[3];
  ushort* Xe = (ushort*)d_ws;
  ushort* We = (ushort*)((char*)d_ws + WS_WE_OFF);
  float* wnorm = (float*)((char*)d_ws + WS_WNORM_OFF);
  float* xnorm = (float*)((char*)d_ws + WS_XNORM_OFF);
  unsigned long long* best = (unsigned long long*)((char*)d_ws + WS_BEST_OFF);
  unsigned* ctrl = (unsigned*)((char*)d_ws + WS_CTRL_OFF);

  hipMemsetAsync(ctrl, 0, 256, stream);
  fused_kernel<<<NBLK, 256, 0, stream>>>(x, w1, w2, w3, Xe, We, wnorm, xnorm,
                                         best, ctrl, (float*)d_out);
}

// Round 10
// 163.205 us; speedup vs baseline: 3.4676x; 2.1790x over previous
//
#include <hip/hip_runtime.h>
#include <hip/hip_fp16.h>
#include <stdint.h>

#define DIM 256
#define KE  768   // expanded K in the GEMM (3 segments x 256)

typedef _Float16 half8 __attribute__((ext_vector_type(8)));
typedef float floatx4 __attribute__((ext_vector_type(4)));

// Workspace layout (bytes) — deduped segments, stride 512 per row:
//   Xe    : 8192*512 ushort @ 0          (8,388,608)   [xh | xl*2^11]
//   We    : 5376*512 ushort @ 8388608    (5,505,024)   [wh | wl*2^11]
//   wnorm : 5376 float      @ 13893632
//   xnorm : 8192 float      @ 13915136
//   best  : 24576 u64       @ 13947904   (level*8192+row) packed (d2<<32)|idx
#define WS_WE_OFF    8388608
#define WS_WNORM_OFF 13893632
#define WS_XNORM_OFF 13915136
#define WS_BEST_OFF  13947904

// One wave per row: fp32 norm + fp16 hi/lo split, layout [h | l*2^11].
// GEMM segment map (K=768): k<256: xh*wh ; 256..511: xh*wl2 ; >=512: xl2*wh
//   => acc = 2^11*dot after the k0==256 rescale of the hh partial.
// Also initializes best[] (blocks 0..95): no separate memset dispatch.
__global__ __launch_bounds__(256) void conv_kernel(
    const float* __restrict__ x, const float* __restrict__ w1,
    const float* __restrict__ w2, const float* __restrict__ w3,
    ushort* __restrict__ Xe, ushort* __restrict__ We,
    float* __restrict__ wnorm, float* __restrict__ xnorm,
    unsigned long long* __restrict__ best) {
  if (blockIdx.x < 96) best[blockIdx.x * 256 + threadIdx.x] = ~0ull;
  int task = blockIdx.x * 4 + (threadIdx.x >> 6);
  int lane = threadIdx.x & 63;
  const float* src; ushort* dst; float* ndst;
  if (task < 8192) {
    src = x + (size_t)task * DIM; dst = Xe + (size_t)task * 512;
    ndst = xnorm + task;
  } else {
    int wi = task - 8192;
    if (wi < 256)       src = w1 + (size_t)wi * DIM;
    else if (wi < 1280) src = w2 + (size_t)(wi - 256) * DIM;
    else                src = w3 + (size_t)(wi - 1280) * DIM;
    dst = We + (size_t)wi * 512; ndst = wnorm + wi;
  }
  float4 v = *(const float4*)(src + lane * 4);
  float fv[4] = {v.x, v.y, v.z, v.w};
  float s = fv[0]*fv[0] + fv[1]*fv[1] + fv[2]*fv[2] + fv[3]*fv[3];
  #pragma unroll
  for (int o = 32; o > 0; o >>= 1) s += __shfl_xor(s, o);
  if (lane == 0) *ndst = s;

  ushort h[4], l[4];
  #pragma unroll
  for (int e = 0; e < 4; ++e) {
    __half hh = __float2half(fv[e]);
    float hf = __half2float(hh);
    __half ll = __float2half((fv[e] - hf) * 2048.0f);  // scaled lo: no denorms
    h[e] = __half_as_ushort(hh);
    l[e] = __half_as_ushort(ll);
  }
  *(ushort4*)(dst + lane * 4)       = make_ushort4(h[0], h[1], h[2], h[3]);
  *(ushort4*)(dst + 256 + lane * 4) = make_ushort4(l[0], l[1], l[2], l[3]);
}

// 128x128 tile MFMA GEMM over K=768 (3 segments from the 512-wide deduped
// rows) with fused per-row argmin. LDS exactly 32KB (red[] aliased into As
// after the K-loop) -> 5 blocks/CU. Proven structure (round 5: 97.7us).
// grid.x = 42 col-blocks (2 | 8 | 32 per level), grid.y = 64 row-blocks.
__global__ __launch_bounds__(256) void gemm_kernel(
    const ushort* __restrict__ Xe, const ushort* __restrict__ We,
    const float* __restrict__ xnorm, const float* __restrict__ wnorm,
    unsigned long long* __restrict__ best) {
  __shared__ __align__(16) ushort As[128 * 64];  // 16KB, XOR-swizzled chunks
  __shared__ __align__(16) ushort Bs[128 * 64];
  // red[2][128] u64 (2 KB) aliases As: first written after the K-loop's
  // final __syncthreads(), when no wave reads As anymore.
  unsigned long long (*red)[128] = (unsigned long long (*)[128])As;

  const int cb = blockIdx.x;
  const int r0 = blockIdx.y * 128;
  const int n0 = cb * 128;
  int level, lbase;
  if (cb < 2)       { level = 0; lbase = 0; }
  else if (cb < 10) { level = 1; lbase = 256; }
  else              { level = 2; lbase = 1280; }

  const int t = threadIdx.x;
  const int w = t >> 6;
  const int lane = t & 63;
  const int ln = lane & 15, q = lane >> 4;
  const int wm = (w >> 1) * 64, wn = (w & 1) * 64;

  floatx4 acc[4][4];
  #pragma unroll
  for (int i = 0; i < 4; ++i)
    #pragma unroll
    for (int j = 0; j < 4; ++j) acc[i][j] = (floatx4)0.0f;

  for (int k0 = 0; k0 < KE; k0 += 64) {
    if (k0 == 256) {  // hh done: scale so cross terms (pre-scaled 2^11) match
      #pragma unroll
      for (int i = 0; i < 4; ++i)
        #pragma unroll
        for (int j = 0; j < 4; ++j) acc[i][j] *= 2048.0f;
    }
    // Segment source offsets within the 512-wide rows (wave-uniform):
    // A: xh for k0<512, xl2 for k0>=512 ; B: wh, wl2, wh.
    const int ak0 = (k0 < 512) ? (k0 & 255) : (k0 - 256);
    const int bk0 = (k0 < 512) ? k0 : (k0 - 512);
    // Stage A and B tiles: 1024 16B-chunks each; chunk p holds global
    // (row m = p>>3, colchunk c = (p&7)^(m&7)) -> conflict-free frag reads.
    #pragma unroll
    for (int it = 0; it < 4; ++it) {
      int p = it * 256 + t;
      int m = p >> 3;
      int c = (p & 7) ^ (m & 7);
      const ushort* ga = Xe + (size_t)(r0 + m) * 512 + ak0 + c * 8;
      const ushort* gb = We + (size_t)(n0 + m) * 512 + bk0 + c * 8;
      int lbc = it * 256 + (t & 192);  // wave-uniform
      __builtin_amdgcn_global_load_lds(
          (const __attribute__((address_space(1))) void*)ga,
          (__attribute__((address_space(3))) void*)(As + lbc * 8), 16, 0, 0);
      __builtin_amdgcn_global_load_lds(
          (const __attribute__((address_space(1))) void*)gb,
          (__attribute__((address_space(3))) void*)(Bs + lbc * 8), 16, 0, 0);
    }
    __syncthreads();
    #pragma unroll
    for (int s = 0; s < 2; ++s) {
      half8 a[4], b[4];
      #pragma unroll
      for (int mt = 0; mt < 4; ++mt) {
        int m = wm + mt * 16 + ln;
        int pos = m * 8 + ((s * 4 + q) ^ (m & 7));
        a[mt] = *(const half8*)&As[pos * 8];
      }
      #pragma unroll
      for (int nt = 0; nt < 4; ++nt) {
        int n = wn + nt * 16 + ln;
        int pos = n * 8 + ((s * 4 + q) ^ (n & 7));
        b[nt] = *(const half8*)&Bs[pos * 8];
      }
      #pragma unroll
      for (int mt = 0; mt < 4; ++mt)
        #pragma unroll
        for (int nt = 0; nt < 4; ++nt)
          acc[mt][nt] = __builtin_amdgcn_mfma_f32_16x16x32_f16(
              a[mt], b[nt], acc[mt][nt], 0, 0, 0);
    }
    __syncthreads();
  }

  // acc = 2^11 * dot. d2 = xn + wn - 2*dot = xn + wn - acc * 2^-10.
  float wnv[4];
  #pragma unroll
  for (int nt = 0; nt < 4; ++nt) wnv[nt] = wnorm[n0 + wn + nt * 16 + ln];

  #pragma unroll
  for (int mt = 0; mt < 4; ++mt) {
    #pragma unroll
    for (int r = 0; r < 4; ++r) {
      int rowl = wm + mt * 16 + q * 4 + r;
      float xnv = xnorm[r0 + rowl];
      unsigned long long bp = ~0ull;
      #pragma unroll
      for (int nt = 0; nt < 4; ++nt) {
        float d2 = fmaxf(xnv + wnv[nt] - acc[mt][nt][r] * 0.0009765625f, 0.0f);
        unsigned col = (unsigned)(n0 + wn + nt * 16 + ln - lbase);
        unsigned long long p =
            ((unsigned long long)__float_as_uint(d2) << 32) | col;
        bp = (p < bp) ? p : bp;
      }
      #pragma unroll
      for (int off = 1; off < 16; off <<= 1) {
        unsigned long long o = __shfl_xor(bp, off);
        bp = (o < bp) ? o : bp;
      }
      if (ln == 0) red[w & 1][rowl] = bp;
    }
  }
  __syncthreads();
  if (t < 128) {
    unsigned long long a = red[0][t], b = red[1][t];
    unsigned long long m = (a < b) ? a : b;
    atomicMin(&best[level * 8192 + r0 + t], m);
  }
}

// Trivial finalize: unpack best -> coords + sqrt(d2). The packed d2 is the
// hi/lo GEMM distance; |sqrt(d2)-exact| ~ 2e-4 << 1.26 threshold, and the
// argmin index itself has matched the reference in every passing round.
__global__ __launch_bounds__(256) void finalize_kernel(
    const unsigned long long* __restrict__ best, float* __restrict__ out) {
  int task = blockIdx.x * 256 + threadIdx.x;   // 96 blocks x 256 = 24576
  int level = task >> 13;
  int row = task & 8191;
  unsigned side = (level == 0) ? 16u : (level == 1) ? 32u : 64u;
  unsigned long long v = best[task];
  unsigned idx = (unsigned)(v & 0xFFFFFFFFull);
  if (idx >= side * side) idx = 0;             // defensive
  float d2 = __uint_as_float((unsigned)(v >> 32));
  out[level * 16384 + row * 2 + 0] = (float)(idx / side);
  out[level * 16384 + row * 2 + 1] = (float)(idx % side);
  out[49152 + level * 8192 + row] = sqrtf(d2);
}

extern "C" void kernel_launch(void* const* d_in, const int* in_sizes, int n_in,
                              void* d_out, int out_size, void* d_ws, size_t ws_size,
                              hipStream_t stream) {
  const float* x  = (const float*)d_in[0];
  const float* w1 = (const float*)d_in[1];
  const float* w2 = (const float*)d_in[2];
  const float* w3 = (const float*)d_in[3];
  ushort* Xe = (ushort*)d_ws;
  ushort* We = (ushort*)((char*)d_ws + WS_WE_OFF);
  float* wnorm = (float*)((char*)d_ws + WS_WNORM_OFF);
  float* xnorm = (float*)((char*)d_ws + WS_XNORM_OFF);
  unsigned long long* best = (unsigned long long*)((char*)d_ws + WS_BEST_OFF);

  conv_kernel<<<3392, 256, 0, stream>>>(x, w1, w2, w3, Xe, We, wnorm, xnorm,
                                        best);
  gemm_kernel<<<dim3(42, 64), 256, 0, stream>>>(Xe, We, xnorm, wnorm, best);
  finalize_kernel<<<96, 256, 0, stream>>>(best, (float*)d_out);
}